// Round 5
// baseline (898.905 us; speedup 1.0000x reference)
//
#include <hip/hip_runtime.h>

#define T_LEN 512
#define OSTRIDE ((size_t)2048 * 512 * 32)  // elements per output copy

__device__ __forceinline__ float rlf(float v, int l) {
  return __int_as_float(__builtin_amdgcn_readlane(__float_as_int(v), l));
}
// quad_perm broadcast of quad-lane sel (0..3): ctrl = sel * 0x55
#define QB(v, pat) __int_as_float(__builtin_amdgcn_mov_dpp(__float_as_int(v), (pat), 0xF, 0xF, false))

// ===========================================================================
// Shared pre-net body: row r of seq -> y3[16]  (32 -> 16 -> 16 -> 16)
// Weights wave-uniform (SMEM loads, K$-cached).
// ===========================================================================
__device__ __forceinline__ void prenet_row(
    const float* __restrict__ sp,
    const float* __restrict__ w1, const float* __restrict__ b1,
    const float* __restrict__ w2, const float* __restrict__ b2,
    const float* __restrict__ w3, const float* __restrict__ b3,
    float y3[16]) {
  float in[32];
#pragma unroll
  for (int q = 0; q < 8; ++q) {
    float4 v = ((const float4*)sp)[q];
    in[q * 4 + 0] = v.x;
    in[q * 4 + 1] = v.y;
    in[q * 4 + 2] = v.z;
    in[q * 4 + 3] = v.w;
  }

  float y1[16];
#pragma unroll
  for (int j = 0; j < 16; ++j) {
    float a0 = b1[j], a1 = 0.f, a2 = 0.f, a3 = 0.f;
#pragma unroll
    for (int k = 0; k < 32; k += 4) {
      a0 = __builtin_fmaf(w1[j * 32 + k + 0], in[k + 0], a0);
      a1 = __builtin_fmaf(w1[j * 32 + k + 1], in[k + 1], a1);
      a2 = __builtin_fmaf(w1[j * 32 + k + 2], in[k + 2], a2);
      a3 = __builtin_fmaf(w1[j * 32 + k + 3], in[k + 3], a3);
    }
    float s = (a0 + a1) + (a2 + a3);
    y1[j] = s >= 0.f ? s : 0.01f * s;
  }

  float y2[16];
#pragma unroll
  for (int j = 0; j < 16; ++j) {
    float a0 = b2[j], a1 = 0.f, a2 = 0.f, a3 = 0.f;
#pragma unroll
    for (int k = 0; k < 16; k += 4) {
      a0 = __builtin_fmaf(w2[j * 16 + k + 0], y1[k + 0], a0);
      a1 = __builtin_fmaf(w2[j * 16 + k + 1], y1[k + 1], a1);
      a2 = __builtin_fmaf(w2[j * 16 + k + 2], y1[k + 2], a2);
      a3 = __builtin_fmaf(w2[j * 16 + k + 3], y1[k + 3], a3);
    }
    float s = (a0 + a1) + (a2 + a3);
    y2[j] = s >= 0.f ? s : 0.01f * s;
  }

#pragma unroll
  for (int j = 0; j < 16; ++j) {
    float a0 = b3[j], a1 = 0.f, a2 = 0.f, a3 = 0.f;
#pragma unroll
    for (int k = 0; k < 16; k += 4) {
      a0 = __builtin_fmaf(w3[j * 16 + k + 0], y2[k + 0], a0);
      a1 = __builtin_fmaf(w3[j * 16 + k + 1], y2[k + 1], a1);
      a2 = __builtin_fmaf(w3[j * 16 + k + 2], y2[k + 2], a2);
      a3 = __builtin_fmaf(w3[j * 16 + k + 3], y2[k + 3], a3);
    }
    y3[j] = (a0 + a1) + (a2 + a3);
  }
}

// ===========================================================================
// Z-PATH kernel 1: pre-net + gate precompute.
// z[r*64+j] = sK(j) * (Wih[j]·y3 + bih[j] + bhh[j]), sK = (j>>4)==2 ? 2 : -1.
// Row t=T-1 of each sample also saved to xstart (decoder start vector).
// ===========================================================================
__global__ __launch_bounds__(256) void prenet_z_kernel(
    const float* __restrict__ seq,
    const float* __restrict__ w1, const float* __restrict__ b1,
    const float* __restrict__ w2, const float* __restrict__ b2,
    const float* __restrict__ w3, const float* __restrict__ b3,
    const float* __restrict__ Wih, const float* __restrict__ bih,
    const float* __restrict__ bhh,
    float* __restrict__ z, float* __restrict__ xstart) {
  const size_t r = (size_t)blockIdx.x * 256 + threadIdx.x;  // < 1,048,576
  float y3[16];
  prenet_row(seq + r * 32, w1, b1, w2, b2, w3, b3, y3);

  float* zp = z + r * 64;
#pragma unroll
  for (int j = 0; j < 64; j += 4) {
    float4 o;
    float* op = (float*)&o;
#pragma unroll
    for (int jj = 0; jj < 4; ++jj) {
      const int g = j + jj;
      const float sK = ((g >> 4) == 2) ? 2.0f : -1.0f;
      float a0 = bih[g] + bhh[g], a1 = 0.f, a2 = 0.f, a3 = 0.f;
#pragma unroll
      for (int k = 0; k < 16; k += 4) {
        a0 = __builtin_fmaf(Wih[g * 16 + k + 0], y3[k + 0], a0);
        a1 = __builtin_fmaf(Wih[g * 16 + k + 1], y3[k + 1], a1);
        a2 = __builtin_fmaf(Wih[g * 16 + k + 2], y3[k + 2], a2);
        a3 = __builtin_fmaf(Wih[g * 16 + k + 3], y3[k + 3], a3);
      }
      op[jj] = sK * ((a0 + a1) + (a2 + a3));
    }
    ((float4*)zp)[j >> 2] = o;
  }

  if ((r & (T_LEN - 1)) == (T_LEN - 1)) {  // t == T-1
    float* xs = xstart + (r >> 9) * 16;
#pragma unroll
    for (int q = 0; q < 4; ++q)
      ((float4*)xs)[q] = make_float4(y3[q * 4 + 0], y3[q * 4 + 1],
                                     y3[q * 4 + 2], y3[q * 4 + 3]);
  }
}

// ===========================================================================
// Z-PATH kernel 2: recurrence.  One wave per sample.
// Encoder: g = z (per-lane VGPR, prefetched 8 steps ahead) + sK*Whh·h.
// Decoder: R4 structure (composed Mr = sK*Wih@W2, fused post/w1 GEMV).
// ===========================================================================
#define ACTBODY()                                                           \
  do {                                                                      \
    float ee = __expf(g);                                                   \
    float rr = __builtin_amdgcn_rcpf(1.0f + ee);                            \
    float act = __builtin_fmaf(sa, rr, sb);                                 \
    float ii = QB(act, 0x00);                                               \
    float ff = QB(act, 0x55);                                               \
    float gg = QB(act, 0xAA);                                               \
    float oo = QB(act, 0xFF);                                               \
    c = __builtin_fmaf(ff, c, ii * gg);                                     \
    float th = __builtin_fmaf(                                              \
        -2.0f, __builtin_amdgcn_rcpf(1.0f + __expf(c + c)), 1.0f);          \
    h = oo * th;                                                            \
    _Pragma("unroll") for (int k = 0; k < 16; ++k) hk[k] = rlf(h, 4 * k);   \
  } while (0)

#define CELLZ(ZV)                                                           \
  do {                                                                      \
    float a0 = (ZV), a1 = 0.f, a2 = 0.f, a3 = 0.f;                          \
    _Pragma("unroll") for (int k = 0; k < 16; k += 4) {                     \
      a0 = __builtin_fmaf(whhr[k + 0], hk[k + 0], a0);                      \
      a1 = __builtin_fmaf(whhr[k + 1], hk[k + 1], a1);                      \
      a2 = __builtin_fmaf(whhr[k + 2], hk[k + 2], a2);                      \
      a3 = __builtin_fmaf(whhr[k + 3], hk[k + 3], a3);                      \
    }                                                                       \
    float g = (a0 + a1) + (a2 + a3);                                        \
    ACTBODY();                                                              \
  } while (0)

#define CELL(WX, XA, BB)                                                    \
  do {                                                                      \
    float a0 = (BB), a1 = 0.f, a2 = 0.f, a3 = 0.f;                          \
    _Pragma("unroll") for (int k = 0; k < 16; k += 4) {                     \
      a0 = __builtin_fmaf(WX[k + 0], XA[k + 0], a0);                        \
      a1 = __builtin_fmaf(WX[k + 1], XA[k + 1], a1);                        \
      a2 = __builtin_fmaf(WX[k + 2], XA[k + 2], a2);                        \
      a3 = __builtin_fmaf(WX[k + 3], XA[k + 3], a3);                        \
    }                                                                       \
    _Pragma("unroll") for (int k = 0; k < 16; k += 4) {                     \
      a0 = __builtin_fmaf(whhr[k + 0], hk[k + 0], a0);                      \
      a1 = __builtin_fmaf(whhr[k + 1], hk[k + 1], a1);                      \
      a2 = __builtin_fmaf(whhr[k + 2], hk[k + 2], a2);                      \
      a3 = __builtin_fmaf(whhr[k + 3], hk[k + 3], a3);                      \
    }                                                                       \
    float g = (a0 + a1) + (a2 + a3);                                        \
    ACTBODY();                                                              \
  } while (0)

__global__ __launch_bounds__(256) void lstm_rec_z_kernel(
    const float* __restrict__ Whh, const float* __restrict__ Wih,
    const float* __restrict__ bih, const float* __restrict__ bhh,
    const float* __restrict__ hw1, const float* __restrict__ hb1,
    const float* __restrict__ hw2, const float* __restrict__ hb2,
    const float* __restrict__ pw, const float* __restrict__ pb,
    const float* __restrict__ z, const float* __restrict__ xstart,
    float* __restrict__ out) {
  const int lane = threadIdx.x & 63;
  const int bu =
      __builtin_amdgcn_readfirstlane(blockIdx.x * 4 + (threadIdx.x >> 6));
  const int hr = lane >> 2;             // h index 0..15 (quad id)
  const int gi = (lane & 3) * 16 + hr;  // gate row 0..63
  const bool isT = (lane & 3) == 2;     // quad-lane 2 = g gate (tanh)

  const float sK = isT ? 2.0f : -1.0f;
  const float sa = isT ? -2.0f : 1.0f;
  const float sb = isT ? 1.0f : 0.0f;

  float whhr[16];
#pragma unroll
  for (int k = 0; k < 16; ++k) whhr[k] = Whh[gi * 16 + k] * sK;

  float h = 0.f, c = 0.f;
  float hk[16];
#pragma unroll
  for (int k = 0; k < 16; ++k) hk[k] = 0.f;

  // ---------------- encoder: 512 steps, z prefetched 8 ahead ----------------
  const float* zb = z + (size_t)bu * (T_LEN * 64) + gi;
  float zq[8];
#pragma unroll
  for (int u = 0; u < 8; ++u) zq[u] = zb[(size_t)u * 64];

  for (int t0 = 0; t0 < T_LEN; t0 += 8) {
#pragma unroll
    for (int u = 0; u < 8; ++u) {
      CELLZ(zq[u]);
      int tn = t0 + u + 8;
      tn = tn < T_LEN ? tn : (T_LEN - 1);  // tail reload of row 511, harmless
      zq[u] = zb[(size_t)tn * 64];
    }
  }

  // ---------------- decoder setup ----------------
  float wihr[16];
#pragma unroll
  for (int k = 0; k < 16; ++k) wihr[k] = Wih[gi * 16 + k] * sK;
  const float bias = (bih[gi] + bhh[gi]) * sK;

  // Fused GEMV rows: lanes 0..31 post_w row=lane; 32..63 h2l_w1 row=lane&15.
  const int mrow = (lane < 32) ? lane : (lane & 15);
  const float* msrc = (lane < 32) ? (pw + mrow * 16) : (hw1 + mrow * 16);
  const float mbias = (lane < 32) ? pb[mrow] : hb1[mrow];
  const float sl = (lane < 32) ? 1.0f : 0.01f;
  float mr[16];
#pragma unroll
  for (int k = 0; k < 16; ++k) mr[k] = msrc[k];

  // Composed matrix Mr = (sK*Wih) @ W2; mbias2 = bias + (sK*Wih)·b2.
  float Mr[16];
#pragma unroll
  for (int k = 0; k < 16; ++k) Mr[k] = 0.f;
#pragma unroll
  for (int j = 0; j < 16; ++j) {
#pragma unroll
    for (int k = 0; k < 16; ++k)
      Mr[k] = __builtin_fmaf(wihr[j], hw2[j * 16 + k], Mr[k]);
  }
  float mbias2 = bias;
#pragma unroll
  for (int j = 0; j < 16; ++j) mbias2 = __builtin_fmaf(wihr[j], hb2[j], mbias2);

  // start0
  float xk[16];
  {
    const float* src = xstart + (size_t)bu * 16;
#pragma unroll
    for (int k = 0; k < 16; ++k) xk[k] = src[k];
  }

  float uk[16];
  const size_t obase = (size_t)bu * (T_LEN * 32) + (lane & 31);

  // ---------------- decoder: 512 steps ----------------
  CELL(wihr, xk, bias);

  for (int t = 0; t < T_LEN; ++t) {
    float p0 = mbias, p1 = 0.f, p2 = 0.f, p3 = 0.f;
#pragma unroll
    for (int k = 0; k < 16; k += 4) {
      p0 = __builtin_fmaf(mr[k + 0], hk[k + 0], p0);
      p1 = __builtin_fmaf(mr[k + 1], hk[k + 1], p1);
      p2 = __builtin_fmaf(mr[k + 2], hk[k + 2], p2);
      p3 = __builtin_fmaf(mr[k + 3], hk[k + 3], p3);
    }
    float y0 = (p0 + p1) + (p2 + p3);
    float yv = fmaxf(y0, y0 * sl);

    if (lane < 32) {
      const size_t off = obase + (size_t)(T_LEN - 1 - t) * 32;
      out[off] = yv;
      out[off + OSTRIDE] = yv;
    }

    if (t + 1 < T_LEN) {
#pragma unroll
      for (int k = 0; k < 16; ++k) uk[k] = rlf(yv, 32 + k);
      CELL(Mr, uk, mbias2);
    }
  }
}

// ===========================================================================
// FALLBACK (x-path) — R4 kernels verbatim, used if ws_size < z requirement.
// ===========================================================================
__global__ __launch_bounds__(256) void prenet_kernel(
    const float* __restrict__ seq,
    const float* __restrict__ w1, const float* __restrict__ b1,
    const float* __restrict__ w2, const float* __restrict__ b2,
    const float* __restrict__ w3, const float* __restrict__ b3,
    float* __restrict__ xws) {
  const size_t r = (size_t)blockIdx.x * 256 + threadIdx.x;
  float y3[16];
  prenet_row(seq + r * 32, w1, b1, w2, b2, w3, b3, y3);
  float* op = xws + r * 16;
#pragma unroll
  for (int q = 0; q < 4; ++q)
    ((float4*)op)[q] =
        make_float4(y3[q * 4 + 0], y3[q * 4 + 1], y3[q * 4 + 2], y3[q * 4 + 3]);
}

__global__ __launch_bounds__(256) void lstm_rec_kernel(
    const float* __restrict__ Wih, const float* __restrict__ Whh,
    const float* __restrict__ bih, const float* __restrict__ bhh,
    const float* __restrict__ hw1, const float* __restrict__ hb1,
    const float* __restrict__ hw2, const float* __restrict__ hb2,
    const float* __restrict__ pw, const float* __restrict__ pb,
    const float* __restrict__ xws, float* __restrict__ out) {
  const int lane = threadIdx.x & 63;
  const int bu =
      __builtin_amdgcn_readfirstlane(blockIdx.x * 4 + (threadIdx.x >> 6));
  const int hr = lane >> 2;
  const int gi = (lane & 3) * 16 + hr;
  const bool isT = (lane & 3) == 2;

  const float sK = isT ? 2.0f : -1.0f;
  const float sa = isT ? -2.0f : 1.0f;
  const float sb = isT ? 1.0f : 0.0f;

  float wihr[16], whhr[16];
#pragma unroll
  for (int k = 0; k < 16; ++k) {
    wihr[k] = Wih[gi * 16 + k] * sK;
    whhr[k] = Whh[gi * 16 + k] * sK;
  }
  const float bias = (bih[gi] + bhh[gi]) * sK;

  float h = 0.f, c = 0.f;
  float hk[16];
#pragma unroll
  for (int k = 0; k < 16; ++k) hk[k] = 0.f;

  const float* xb = xws + (size_t)bu * (T_LEN * 16);

  float xA[16], xB[16];
#pragma unroll
  for (int k = 0; k < 16; ++k) xA[k] = xb[k];
  for (int t = 0; t < T_LEN; t += 2) {
    const float* n1 = xb + (size_t)(t + 1) * 16;
#pragma unroll
    for (int k = 0; k < 16; ++k) xB[k] = n1[k];
    CELL(wihr, xA, bias);
    const int t2 = (t + 2 < T_LEN) ? (t + 2) : (T_LEN - 1);
    const float* n2 = xb + (size_t)t2 * 16;
#pragma unroll
    for (int k = 0; k < 16; ++k) xA[k] = n2[k];
    CELL(wihr, xB, bias);
  }

  const int mrow = (lane < 32) ? lane : (lane & 15);
  const float* msrc = (lane < 32) ? (pw + mrow * 16) : (hw1 + mrow * 16);
  const float mbias = (lane < 32) ? pb[mrow] : hb1[mrow];
  const float sl = (lane < 32) ? 1.0f : 0.01f;
  float mr[16];
#pragma unroll
  for (int k = 0; k < 16; ++k) mr[k] = msrc[k];

  float Mr[16];
#pragma unroll
  for (int k = 0; k < 16; ++k) Mr[k] = 0.f;
#pragma unroll
  for (int j = 0; j < 16; ++j) {
#pragma unroll
    for (int k = 0; k < 16; ++k)
      Mr[k] = __builtin_fmaf(wihr[j], hw2[j * 16 + k], Mr[k]);
  }
  float mbias2 = bias;
#pragma unroll
  for (int j = 0; j < 16; ++j) mbias2 = __builtin_fmaf(wihr[j], hb2[j], mbias2);

  float xk[16];
  {
    const float* src = xb + (size_t)(T_LEN - 1) * 16;
#pragma unroll
    for (int k = 0; k < 16; ++k) xk[k] = src[k];
  }

  float uk[16];
  const size_t obase = (size_t)bu * (T_LEN * 32) + (lane & 31);

  CELL(wihr, xk, bias);

  for (int t = 0; t < T_LEN; ++t) {
    float p0 = mbias, p1 = 0.f, p2 = 0.f, p3 = 0.f;
#pragma unroll
    for (int k = 0; k < 16; k += 4) {
      p0 = __builtin_fmaf(mr[k + 0], hk[k + 0], p0);
      p1 = __builtin_fmaf(mr[k + 1], hk[k + 1], p1);
      p2 = __builtin_fmaf(mr[k + 2], hk[k + 2], p2);
      p3 = __builtin_fmaf(mr[k + 3], hk[k + 3], p3);
    }
    float y0 = (p0 + p1) + (p2 + p3);
    float yv = fmaxf(y0, y0 * sl);

    if (lane < 32) {
      const size_t off = obase + (size_t)(T_LEN - 1 - t) * 32;
      out[off] = yv;
      out[off + OSTRIDE] = yv;
    }

    if (t + 1 < T_LEN) {
#pragma unroll
      for (int k = 0; k < 16; ++k) uk[k] = rlf(yv, 32 + k);
      CELL(Mr, uk, mbias2);
    }
  }
}

extern "C" void kernel_launch(void* const* d_in, const int* in_sizes, int n_in,
                              void* d_out, int out_size, void* d_ws, size_t ws_size,
                              hipStream_t stream) {
  const float* seq = (const float*)d_in[0];
  const float* pre_w1 = (const float*)d_in[1];
  const float* pre_b1 = (const float*)d_in[2];
  const float* pre_w2 = (const float*)d_in[3];
  const float* pre_b2 = (const float*)d_in[4];
  const float* pre_w3 = (const float*)d_in[5];
  const float* pre_b3 = (const float*)d_in[6];
  const float* enc_Wih = (const float*)d_in[7];
  const float* enc_Whh = (const float*)d_in[8];
  const float* enc_bih = (const float*)d_in[9];
  const float* enc_bhh = (const float*)d_in[10];
  const float* h2l_w1 = (const float*)d_in[11];
  const float* h2l_b1 = (const float*)d_in[12];
  const float* h2l_w2 = (const float*)d_in[13];
  const float* h2l_b2 = (const float*)d_in[14];
  const float* post_w = (const float*)d_in[15];
  const float* post_b = (const float*)d_in[16];

  // z-path workspace: z (1M x 64 fp32 = 256 MiB) + xstart (2048 x 16 fp32)
  const size_t zbytes = (size_t)1048576 * 64 * 4;
  const size_t need = zbytes + (size_t)2048 * 16 * 4;

  if (ws_size >= need) {
    float* z = (float*)d_ws;
    float* xstart = (float*)((char*)d_ws + zbytes);

    prenet_z_kernel<<<dim3(4096), dim3(256), 0, stream>>>(
        seq, pre_w1, pre_b1, pre_w2, pre_b2, pre_w3, pre_b3, enc_Wih, enc_bih,
        enc_bhh, z, xstart);

    lstm_rec_z_kernel<<<dim3(512), dim3(256), 0, stream>>>(
        enc_Whh, enc_Wih, enc_bih, enc_bhh, h2l_w1, h2l_b1, h2l_w2, h2l_b2,
        post_w, post_b, z, xstart, (float*)d_out);
  } else {
    float* xws = (float*)d_ws;  // (B*T, 16) fp32 = 64 MiB

    prenet_kernel<<<dim3(4096), dim3(256), 0, stream>>>(
        seq, pre_w1, pre_b1, pre_w2, pre_b2, pre_w3, pre_b3, xws);

    lstm_rec_kernel<<<dim3(512), dim3(256), 0, stream>>>(
        enc_Wih, enc_Whh, enc_bih, enc_bhh, h2l_w1, h2l_b1, h2l_w2, h2l_b2,
        post_w, post_b, xws, (float*)d_out);
  }
}

// Round 6
// 721.015 us; speedup vs baseline: 1.2467x; 1.2467x over previous
//
#include <hip/hip_runtime.h>

#define T_LEN 512
#define OSTRIDE ((size_t)2048 * 512 * 32)  // elements per output copy

__device__ __forceinline__ float rlf(float v, int l) {
  return __int_as_float(__builtin_amdgcn_readlane(__float_as_int(v), l));
}
// quad_perm broadcast of quad-lane sel (0..3): ctrl = sel * 0x55
#define QB(v, pat) __int_as_float(__builtin_amdgcn_mov_dpp(__float_as_int(v), (pat), 0xF, 0xF, false))

// ===========================================================================
// Setup kernel (1 block, 64 threads): compose the z-gate matrix.
//   W_z[g][k] = sK(g) * sum_j Wih[g][j] * W3[j][k]
//   b_z[g]    = sK(g) * (Wih[g]·b3 + bih[g] + bhh[g])
// Valid because pre-net layer 3 has NO activation: z = W_z@y2 + b_z.
// ===========================================================================
__global__ __launch_bounds__(64) void setup_kernel(
    const float* __restrict__ Wih, const float* __restrict__ bih,
    const float* __restrict__ bhh, const float* __restrict__ w3,
    const float* __restrict__ b3, float* __restrict__ Wz,
    float* __restrict__ Bz) {
  const int g = threadIdx.x;  // 0..63
  const float sK = ((g >> 4) == 2) ? 2.0f : -1.0f;
  float acc[16];
#pragma unroll
  for (int k = 0; k < 16; ++k) acc[k] = 0.f;
  float bz = bih[g] + bhh[g];
#pragma unroll
  for (int j = 0; j < 16; ++j) {
    const float wij = Wih[g * 16 + j];
#pragma unroll
    for (int k = 0; k < 16; ++k)
      acc[k] = __builtin_fmaf(wij, w3[j * 16 + k], acc[k]);
    bz = __builtin_fmaf(wij, b3[j], bz);
  }
#pragma unroll
  for (int k = 0; k < 16; ++k) Wz[g * 16 + k] = sK * acc[k];
  Bz[g] = sK * bz;
}

// ===========================================================================
// Pre-net + z kernel.  Block = 256 rows.
// Phase A: thread = row; layers 1-2 (768 FMA) -> y2 into LDS [256][20].
//          (y3 + xstart only for the t==T-1 row.)
// Phase B: thread t -> gate g=t&63, wave id w=t>>6; 64 iterations m:
//          row = 4m+w (WAVE-UNIFORM -> broadcast ds_read_b128),
//          z = W_z[g]·y2 + b_z[g], store block-coalesced
//          (offset rblk*64 + 256m + t : consecutive threads, consecutive).
// ===========================================================================
__global__ __launch_bounds__(256) void prenet_y2z_kernel(
    const float* __restrict__ seq,
    const float* __restrict__ w1, const float* __restrict__ b1,
    const float* __restrict__ w2, const float* __restrict__ b2,
    const float* __restrict__ w3, const float* __restrict__ b3,
    const float* __restrict__ Wz, const float* __restrict__ Bz,
    float* __restrict__ z, float* __restrict__ xstart) {
  __shared__ float y2s[256 * 20];  // row stride 20 floats (80 B, 16-aligned)
  const int tid = threadIdx.x;
  const size_t rblk = (size_t)blockIdx.x * 256;
  const size_t r = rblk + tid;

  // ---------------- phase A: layers 1-2 ----------------
  {
    const float* sp = seq + r * 32;
    float in[32];
#pragma unroll
    for (int q = 0; q < 8; ++q) {
      float4 v = ((const float4*)sp)[q];
      in[q * 4 + 0] = v.x;
      in[q * 4 + 1] = v.y;
      in[q * 4 + 2] = v.z;
      in[q * 4 + 3] = v.w;
    }

    float y1[16];
#pragma unroll
    for (int j = 0; j < 16; ++j) {
      float a0 = b1[j], a1 = 0.f, a2 = 0.f, a3 = 0.f;
#pragma unroll
      for (int k = 0; k < 32; k += 4) {
        a0 = __builtin_fmaf(w1[j * 32 + k + 0], in[k + 0], a0);
        a1 = __builtin_fmaf(w1[j * 32 + k + 1], in[k + 1], a1);
        a2 = __builtin_fmaf(w1[j * 32 + k + 2], in[k + 2], a2);
        a3 = __builtin_fmaf(w1[j * 32 + k + 3], in[k + 3], a3);
      }
      float s = (a0 + a1) + (a2 + a3);
      y1[j] = s >= 0.f ? s : 0.01f * s;
    }

    float y2[16];
#pragma unroll
    for (int j = 0; j < 16; ++j) {
      float a0 = b2[j], a1 = 0.f, a2 = 0.f, a3 = 0.f;
#pragma unroll
      for (int k = 0; k < 16; k += 4) {
        a0 = __builtin_fmaf(w2[j * 16 + k + 0], y1[k + 0], a0);
        a1 = __builtin_fmaf(w2[j * 16 + k + 1], y1[k + 1], a1);
        a2 = __builtin_fmaf(w2[j * 16 + k + 2], y1[k + 2], a2);
        a3 = __builtin_fmaf(w2[j * 16 + k + 3], y1[k + 3], a3);
      }
      float s = (a0 + a1) + (a2 + a3);
      y2[j] = s >= 0.f ? s : 0.01f * s;
    }

    float* yp = &y2s[tid * 20];
#pragma unroll
    for (int q = 0; q < 4; ++q)
      ((float4*)yp)[q] = make_float4(y2[q * 4 + 0], y2[q * 4 + 1],
                                     y2[q * 4 + 2], y2[q * 4 + 3]);

    // xstart (decoder start vector) needs true y3, only at t == T-1
    if ((r & (T_LEN - 1)) == (T_LEN - 1)) {
      float y3[16];
#pragma unroll
      for (int j = 0; j < 16; ++j) {
        float a0 = b3[j], a1 = 0.f, a2 = 0.f, a3 = 0.f;
#pragma unroll
        for (int k = 0; k < 16; k += 4) {
          a0 = __builtin_fmaf(w3[j * 16 + k + 0], y2[k + 0], a0);
          a1 = __builtin_fmaf(w3[j * 16 + k + 1], y2[k + 1], a1);
          a2 = __builtin_fmaf(w3[j * 16 + k + 2], y2[k + 2], a2);
          a3 = __builtin_fmaf(w3[j * 16 + k + 3], y2[k + 3], a3);
        }
        y3[j] = (a0 + a1) + (a2 + a3);
      }
      float* xs = xstart + (r >> 9) * 16;
#pragma unroll
      for (int q = 0; q < 4; ++q)
        ((float4*)xs)[q] = make_float4(y3[q * 4 + 0], y3[q * 4 + 1],
                                       y3[q * 4 + 2], y3[q * 4 + 3]);
    }
  }
  __syncthreads();

  // ---------------- phase B: z-gate GEMV, coalesced ----------------
  const int g = tid & 63;
  const int w = tid >> 6;

  float wz[16];
  {
    const float4* wzv = (const float4*)(Wz + g * 16);
#pragma unroll
    for (int q = 0; q < 4; ++q) {
      float4 v = wzv[q];
      wz[q * 4 + 0] = v.x;
      wz[q * 4 + 1] = v.y;
      wz[q * 4 + 2] = v.z;
      wz[q * 4 + 3] = v.w;
    }
  }
  const float bz = Bz[g];

  float* zo = z + rblk * 64 + tid;  // + 256*m per iteration (coalesced)
#pragma unroll 4
  for (int m = 0; m < 64; ++m) {
    const float* yp = &y2s[(4 * m + w) * 20];  // wave-uniform -> broadcast
    float a0 = bz, a1 = 0.f, a2 = 0.f, a3 = 0.f;
#pragma unroll
    for (int q = 0; q < 4; ++q) {
      float4 v = ((const float4*)yp)[q];
      a0 = __builtin_fmaf(wz[q * 4 + 0], v.x, a0);
      a1 = __builtin_fmaf(wz[q * 4 + 1], v.y, a1);
      a2 = __builtin_fmaf(wz[q * 4 + 2], v.z, a2);
      a3 = __builtin_fmaf(wz[q * 4 + 3], v.w, a3);
    }
    zo[m * 256] = (a0 + a1) + (a2 + a3);
  }
}

// ===========================================================================
// Recurrence kernel — UNCHANGED from R5 (352 us, verified).
// ===========================================================================
#define ACTBODY()                                                           \
  do {                                                                      \
    float ee = __expf(g);                                                   \
    float rr = __builtin_amdgcn_rcpf(1.0f + ee);                            \
    float act = __builtin_fmaf(sa, rr, sb);                                 \
    float ii = QB(act, 0x00);                                               \
    float ff = QB(act, 0x55);                                               \
    float gg = QB(act, 0xAA);                                               \
    float oo = QB(act, 0xFF);                                               \
    c = __builtin_fmaf(ff, c, ii * gg);                                     \
    float th = __builtin_fmaf(                                              \
        -2.0f, __builtin_amdgcn_rcpf(1.0f + __expf(c + c)), 1.0f);          \
    h = oo * th;                                                            \
    _Pragma("unroll") for (int k = 0; k < 16; ++k) hk[k] = rlf(h, 4 * k);   \
  } while (0)

#define CELLZ(ZV)                                                           \
  do {                                                                      \
    float a0 = (ZV), a1 = 0.f, a2 = 0.f, a3 = 0.f;                          \
    _Pragma("unroll") for (int k = 0; k < 16; k += 4) {                     \
      a0 = __builtin_fmaf(whhr[k + 0], hk[k + 0], a0);                      \
      a1 = __builtin_fmaf(whhr[k + 1], hk[k + 1], a1);                      \
      a2 = __builtin_fmaf(whhr[k + 2], hk[k + 2], a2);                      \
      a3 = __builtin_fmaf(whhr[k + 3], hk[k + 3], a3);                      \
    }                                                                       \
    float g = (a0 + a1) + (a2 + a3);                                        \
    ACTBODY();                                                              \
  } while (0)

#define CELL(WX, XA, BB)                                                    \
  do {                                                                      \
    float a0 = (BB), a1 = 0.f, a2 = 0.f, a3 = 0.f;                          \
    _Pragma("unroll") for (int k = 0; k < 16; k += 4) {                     \
      a0 = __builtin_fmaf(WX[k + 0], XA[k + 0], a0);                        \
      a1 = __builtin_fmaf(WX[k + 1], XA[k + 1], a1);                        \
      a2 = __builtin_fmaf(WX[k + 2], XA[k + 2], a2);                        \
      a3 = __builtin_fmaf(WX[k + 3], XA[k + 3], a3);                        \
    }                                                                       \
    _Pragma("unroll") for (int k = 0; k < 16; k += 4) {                     \
      a0 = __builtin_fmaf(whhr[k + 0], hk[k + 0], a0);                      \
      a1 = __builtin_fmaf(whhr[k + 1], hk[k + 1], a1);                      \
      a2 = __builtin_fmaf(whhr[k + 2], hk[k + 2], a2);                      \
      a3 = __builtin_fmaf(whhr[k + 3], hk[k + 3], a3);                      \
    }                                                                       \
    float g = (a0 + a1) + (a2 + a3);                                        \
    ACTBODY();                                                              \
  } while (0)

__global__ __launch_bounds__(256) void lstm_rec_z_kernel(
    const float* __restrict__ Whh, const float* __restrict__ Wih,
    const float* __restrict__ bih, const float* __restrict__ bhh,
    const float* __restrict__ hw1, const float* __restrict__ hb1,
    const float* __restrict__ hw2, const float* __restrict__ hb2,
    const float* __restrict__ pw, const float* __restrict__ pb,
    const float* __restrict__ z, const float* __restrict__ xstart,
    float* __restrict__ out) {
  const int lane = threadIdx.x & 63;
  const int bu =
      __builtin_amdgcn_readfirstlane(blockIdx.x * 4 + (threadIdx.x >> 6));
  const int hr = lane >> 2;             // h index 0..15 (quad id)
  const int gi = (lane & 3) * 16 + hr;  // gate row 0..63
  const bool isT = (lane & 3) == 2;     // quad-lane 2 = g gate (tanh)

  const float sK = isT ? 2.0f : -1.0f;
  const float sa = isT ? -2.0f : 1.0f;
  const float sb = isT ? 1.0f : 0.0f;

  float whhr[16];
#pragma unroll
  for (int k = 0; k < 16; ++k) whhr[k] = Whh[gi * 16 + k] * sK;

  float h = 0.f, c = 0.f;
  float hk[16];
#pragma unroll
  for (int k = 0; k < 16; ++k) hk[k] = 0.f;

  // ---------------- encoder: 512 steps, z prefetched 8 ahead ----------------
  const float* zb = z + (size_t)bu * (T_LEN * 64) + gi;
  float zq[8];
#pragma unroll
  for (int u = 0; u < 8; ++u) zq[u] = zb[(size_t)u * 64];

  for (int t0 = 0; t0 < T_LEN; t0 += 8) {
#pragma unroll
    for (int u = 0; u < 8; ++u) {
      CELLZ(zq[u]);
      int tn = t0 + u + 8;
      tn = tn < T_LEN ? tn : (T_LEN - 1);  // tail reload of row 511, harmless
      zq[u] = zb[(size_t)tn * 64];
    }
  }

  // ---------------- decoder setup ----------------
  float wihr[16];
#pragma unroll
  for (int k = 0; k < 16; ++k) wihr[k] = Wih[gi * 16 + k] * sK;
  const float bias = (bih[gi] + bhh[gi]) * sK;

  const int mrow = (lane < 32) ? lane : (lane & 15);
  const float* msrc = (lane < 32) ? (pw + mrow * 16) : (hw1 + mrow * 16);
  const float mbias = (lane < 32) ? pb[mrow] : hb1[mrow];
  const float sl = (lane < 32) ? 1.0f : 0.01f;
  float mr[16];
#pragma unroll
  for (int k = 0; k < 16; ++k) mr[k] = msrc[k];

  float Mr[16];
#pragma unroll
  for (int k = 0; k < 16; ++k) Mr[k] = 0.f;
#pragma unroll
  for (int j = 0; j < 16; ++j) {
#pragma unroll
    for (int k = 0; k < 16; ++k)
      Mr[k] = __builtin_fmaf(wihr[j], hw2[j * 16 + k], Mr[k]);
  }
  float mbias2 = bias;
#pragma unroll
  for (int j = 0; j < 16; ++j) mbias2 = __builtin_fmaf(wihr[j], hb2[j], mbias2);

  float xk[16];
  {
    const float* src = xstart + (size_t)bu * 16;
#pragma unroll
    for (int k = 0; k < 16; ++k) xk[k] = src[k];
  }

  float uk[16];
  const size_t obase = (size_t)bu * (T_LEN * 32) + (lane & 31);

  // ---------------- decoder: 512 steps ----------------
  CELL(wihr, xk, bias);

  for (int t = 0; t < T_LEN; ++t) {
    float p0 = mbias, p1 = 0.f, p2 = 0.f, p3 = 0.f;
#pragma unroll
    for (int k = 0; k < 16; k += 4) {
      p0 = __builtin_fmaf(mr[k + 0], hk[k + 0], p0);
      p1 = __builtin_fmaf(mr[k + 1], hk[k + 1], p1);
      p2 = __builtin_fmaf(mr[k + 2], hk[k + 2], p2);
      p3 = __builtin_fmaf(mr[k + 3], hk[k + 3], p3);
    }
    float y0 = (p0 + p1) + (p2 + p3);
    float yv = fmaxf(y0, y0 * sl);

    if (lane < 32) {
      const size_t off = obase + (size_t)(T_LEN - 1 - t) * 32;
      out[off] = yv;
      out[off + OSTRIDE] = yv;
    }

    if (t + 1 < T_LEN) {
#pragma unroll
      for (int k = 0; k < 16; ++k) uk[k] = rlf(yv, 32 + k);
      CELL(Mr, uk, mbias2);
    }
  }
}

// ===========================================================================
// FALLBACK (x-path) — used only if ws_size is too small for the z path.
// ===========================================================================
__device__ __forceinline__ void prenet_row(
    const float* __restrict__ sp,
    const float* __restrict__ w1, const float* __restrict__ b1,
    const float* __restrict__ w2, const float* __restrict__ b2,
    const float* __restrict__ w3, const float* __restrict__ b3,
    float y3[16]) {
  float in[32];
#pragma unroll
  for (int q = 0; q < 8; ++q) {
    float4 v = ((const float4*)sp)[q];
    in[q * 4 + 0] = v.x;
    in[q * 4 + 1] = v.y;
    in[q * 4 + 2] = v.z;
    in[q * 4 + 3] = v.w;
  }
  float y1[16];
#pragma unroll
  for (int j = 0; j < 16; ++j) {
    float a0 = b1[j], a1 = 0.f, a2 = 0.f, a3 = 0.f;
#pragma unroll
    for (int k = 0; k < 32; k += 4) {
      a0 = __builtin_fmaf(w1[j * 32 + k + 0], in[k + 0], a0);
      a1 = __builtin_fmaf(w1[j * 32 + k + 1], in[k + 1], a1);
      a2 = __builtin_fmaf(w1[j * 32 + k + 2], in[k + 2], a2);
      a3 = __builtin_fmaf(w1[j * 32 + k + 3], in[k + 3], a3);
    }
    float s = (a0 + a1) + (a2 + a3);
    y1[j] = s >= 0.f ? s : 0.01f * s;
  }
  float y2[16];
#pragma unroll
  for (int j = 0; j < 16; ++j) {
    float a0 = b2[j], a1 = 0.f, a2 = 0.f, a3 = 0.f;
#pragma unroll
    for (int k = 0; k < 16; k += 4) {
      a0 = __builtin_fmaf(w2[j * 16 + k + 0], y1[k + 0], a0);
      a1 = __builtin_fmaf(w2[j * 16 + k + 1], y1[k + 1], a1);
      a2 = __builtin_fmaf(w2[j * 16 + k + 2], y1[k + 2], a2);
      a3 = __builtin_fmaf(w2[j * 16 + k + 3], y1[k + 3], a3);
    }
    float s = (a0 + a1) + (a2 + a3);
    y2[j] = s >= 0.f ? s : 0.01f * s;
  }
#pragma unroll
  for (int j = 0; j < 16; ++j) {
    float a0 = b3[j], a1 = 0.f, a2 = 0.f, a3 = 0.f;
#pragma unroll
    for (int k = 0; k < 16; k += 4) {
      a0 = __builtin_fmaf(w3[j * 16 + k + 0], y2[k + 0], a0);
      a1 = __builtin_fmaf(w3[j * 16 + k + 1], y2[k + 1], a1);
      a2 = __builtin_fmaf(w3[j * 16 + k + 2], y2[k + 2], a2);
      a3 = __builtin_fmaf(w3[j * 16 + k + 3], y2[k + 3], a3);
    }
    y3[j] = (a0 + a1) + (a2 + a3);
  }
}

__global__ __launch_bounds__(256) void prenet_kernel(
    const float* __restrict__ seq,
    const float* __restrict__ w1, const float* __restrict__ b1,
    const float* __restrict__ w2, const float* __restrict__ b2,
    const float* __restrict__ w3, const float* __restrict__ b3,
    float* __restrict__ xws) {
  const size_t r = (size_t)blockIdx.x * 256 + threadIdx.x;
  float y3[16];
  prenet_row(seq + r * 32, w1, b1, w2, b2, w3, b3, y3);
  float* op = xws + r * 16;
#pragma unroll
  for (int q = 0; q < 4; ++q)
    ((float4*)op)[q] =
        make_float4(y3[q * 4 + 0], y3[q * 4 + 1], y3[q * 4 + 2], y3[q * 4 + 3]);
}

__global__ __launch_bounds__(256) void lstm_rec_kernel(
    const float* __restrict__ Wih, const float* __restrict__ Whh,
    const float* __restrict__ bih, const float* __restrict__ bhh,
    const float* __restrict__ hw1, const float* __restrict__ hb1,
    const float* __restrict__ hw2, const float* __restrict__ hb2,
    const float* __restrict__ pw, const float* __restrict__ pb,
    const float* __restrict__ xws, float* __restrict__ out) {
  const int lane = threadIdx.x & 63;
  const int bu =
      __builtin_amdgcn_readfirstlane(blockIdx.x * 4 + (threadIdx.x >> 6));
  const int hr = lane >> 2;
  const int gi = (lane & 3) * 16 + hr;
  const bool isT = (lane & 3) == 2;

  const float sK = isT ? 2.0f : -1.0f;
  const float sa = isT ? -2.0f : 1.0f;
  const float sb = isT ? 1.0f : 0.0f;

  float wihr[16], whhr[16];
#pragma unroll
  for (int k = 0; k < 16; ++k) {
    wihr[k] = Wih[gi * 16 + k] * sK;
    whhr[k] = Whh[gi * 16 + k] * sK;
  }
  const float bias = (bih[gi] + bhh[gi]) * sK;

  float h = 0.f, c = 0.f;
  float hk[16];
#pragma unroll
  for (int k = 0; k < 16; ++k) hk[k] = 0.f;

  const float* xb = xws + (size_t)bu * (T_LEN * 16);

  float xA[16], xB[16];
#pragma unroll
  for (int k = 0; k < 16; ++k) xA[k] = xb[k];
  for (int t = 0; t < T_LEN; t += 2) {
    const float* n1 = xb + (size_t)(t + 1) * 16;
#pragma unroll
    for (int k = 0; k < 16; ++k) xB[k] = n1[k];
    CELL(wihr, xA, bias);
    const int t2 = (t + 2 < T_LEN) ? (t + 2) : (T_LEN - 1);
    const float* n2 = xb + (size_t)t2 * 16;
#pragma unroll
    for (int k = 0; k < 16; ++k) xA[k] = n2[k];
    CELL(wihr, xB, bias);
  }

  const int mrow = (lane < 32) ? lane : (lane & 15);
  const float* msrc = (lane < 32) ? (pw + mrow * 16) : (hw1 + mrow * 16);
  const float mbias = (lane < 32) ? pb[mrow] : hb1[mrow];
  const float sl = (lane < 32) ? 1.0f : 0.01f;
  float mr[16];
#pragma unroll
  for (int k = 0; k < 16; ++k) mr[k] = msrc[k];

  float Mr[16];
#pragma unroll
  for (int k = 0; k < 16; ++k) Mr[k] = 0.f;
#pragma unroll
  for (int j = 0; j < 16; ++j) {
#pragma unroll
    for (int k = 0; k < 16; ++k)
      Mr[k] = __builtin_fmaf(wihr[j], hw2[j * 16 + k], Mr[k]);
  }
  float mbias2 = bias;
#pragma unroll
  for (int j = 0; j < 16; ++j) mbias2 = __builtin_fmaf(wihr[j], hb2[j], mbias2);

  float xk[16];
  {
    const float* src = xb + (size_t)(T_LEN - 1) * 16;
#pragma unroll
    for (int k = 0; k < 16; ++k) xk[k] = src[k];
  }

  float uk[16];
  const size_t obase = (size_t)bu * (T_LEN * 32) + (lane & 31);

  CELL(wihr, xk, bias);

  for (int t = 0; t < T_LEN; ++t) {
    float p0 = mbias, p1 = 0.f, p2 = 0.f, p3 = 0.f;
#pragma unroll
    for (int k = 0; k < 16; k += 4) {
      p0 = __builtin_fmaf(mr[k + 0], hk[k + 0], p0);
      p1 = __builtin_fmaf(mr[k + 1], hk[k + 1], p1);
      p2 = __builtin_fmaf(mr[k + 2], hk[k + 2], p2);
      p3 = __builtin_fmaf(mr[k + 3], hk[k + 3], p3);
    }
    float y0 = (p0 + p1) + (p2 + p3);
    float yv = fmaxf(y0, y0 * sl);

    if (lane < 32) {
      const size_t off = obase + (size_t)(T_LEN - 1 - t) * 32;
      out[off] = yv;
      out[off + OSTRIDE] = yv;
    }

    if (t + 1 < T_LEN) {
#pragma unroll
      for (int k = 0; k < 16; ++k) uk[k] = rlf(yv, 32 + k);
      CELL(Mr, uk, mbias2);
    }
  }
}

extern "C" void kernel_launch(void* const* d_in, const int* in_sizes, int n_in,
                              void* d_out, int out_size, void* d_ws, size_t ws_size,
                              hipStream_t stream) {
  const float* seq = (const float*)d_in[0];
  const float* pre_w1 = (const float*)d_in[1];
  const float* pre_b1 = (const float*)d_in[2];
  const float* pre_w2 = (const float*)d_in[3];
  const float* pre_b2 = (const float*)d_in[4];
  const float* pre_w3 = (const float*)d_in[5];
  const float* pre_b3 = (const float*)d_in[6];
  const float* enc_Wih = (const float*)d_in[7];
  const float* enc_Whh = (const float*)d_in[8];
  const float* enc_bih = (const float*)d_in[9];
  const float* enc_bhh = (const float*)d_in[10];
  const float* h2l_w1 = (const float*)d_in[11];
  const float* h2l_b1 = (const float*)d_in[12];
  const float* h2l_w2 = (const float*)d_in[13];
  const float* h2l_b2 = (const float*)d_in[14];
  const float* post_w = (const float*)d_in[15];
  const float* post_b = (const float*)d_in[16];

  // z-path workspace: z (1M x 64 fp32 = 256 MiB) + xstart + Wz + Bz
  const size_t zbytes = (size_t)1048576 * 64 * 4;
  const size_t xsbytes = (size_t)2048 * 16 * 4;
  const size_t wzbytes = 64 * 16 * 4;
  const size_t need = zbytes + xsbytes + wzbytes + 64 * 4;

  if (ws_size >= need) {
    float* z = (float*)d_ws;
    float* xstart = (float*)((char*)d_ws + zbytes);
    float* Wz = (float*)((char*)d_ws + zbytes + xsbytes);
    float* Bz = (float*)((char*)d_ws + zbytes + xsbytes + wzbytes);

    setup_kernel<<<dim3(1), dim3(64), 0, stream>>>(
        enc_Wih, enc_bih, enc_bhh, pre_w3, pre_b3, Wz, Bz);

    prenet_y2z_kernel<<<dim3(4096), dim3(256), 0, stream>>>(
        seq, pre_w1, pre_b1, pre_w2, pre_b2, pre_w3, pre_b3, Wz, Bz, z,
        xstart);

    lstm_rec_z_kernel<<<dim3(512), dim3(256), 0, stream>>>(
        enc_Whh, enc_Wih, enc_bih, enc_bhh, h2l_w1, h2l_b1, h2l_w2, h2l_b2,
        post_w, post_b, z, xstart, (float*)d_out);
  } else {
    float* xws = (float*)d_ws;  // (B*T, 16) fp32 = 64 MiB

    prenet_kernel<<<dim3(4096), dim3(256), 0, stream>>>(
        seq, pre_w1, pre_b1, pre_w2, pre_b2, pre_w3, pre_b3, xws);

    lstm_rec_kernel<<<dim3(512), dim3(256), 0, stream>>>(
        enc_Wih, enc_Whh, enc_bih, enc_bhh, h2l_w1, h2l_b1, h2l_w2, h2l_b2,
        post_w, post_b, xws, (float*)d_out);
  }
}